// Round 9
// baseline (1777.458 us; speedup 1.0000x reference)
//
#include <hip/hip_runtime.h>

#define N_NODES 20000
#define N_EDGES 640000
#define E_TOT   (N_EDGES + N_NODES)   /* 660000: edges + self loops */
#define IN_DIM  128
#define HIDDEN  256
#define OUT_DIM 64
#define LOG2E 1.4426950408889634f
#define NSHARD 8

typedef __attribute__((ext_vector_type(2))) float f32x2;

__device__ __forceinline__ unsigned short f2bf(float f) {
    union { float f; unsigned int i; } x; x.f = f;
    unsigned int u = x.i;
    return (unsigned short)((u + 0x7fffu + ((u >> 16) & 1u)) >> 16);  // RTNE
}
__device__ __forceinline__ f32x2 up2(unsigned int p) {   // 2 packed bf16 -> 2 fp32
    f32x2 r;
    r.x = __uint_as_float(p << 16);
    r.y = __uint_as_float(p & 0xffff0000u);
    return r;
}
__device__ __forceinline__ unsigned int pk2(float a, float b) {
    return (unsigned int)f2bf(a) | ((unsigned int)f2bf(b) << 16);
}

// ---------------- CSR build (6 kernels, all O(N*8) phases grid-parallel) ----------------

__global__ void zero_cnt8_kernel(int* __restrict__ cnt8) {
    int i = blockIdx.x * blockDim.x + threadIdx.x;
    if (i < NSHARD * N_NODES) cnt8[i] = 0;
}

__global__ void count_kernel(const int* __restrict__ edge_dst, int* __restrict__ cnt8) {
    int i = blockIdx.x * blockDim.x + threadIdx.x;
    if (i >= E_TOT) return;
    int shard = blockIdx.x & (NSHARD - 1);
    int d = (i < N_EDGES) ? edge_dst[i] : (i - N_EDGES);   // implicit self-loop tail
    atomicAdd(&cnt8[shard * N_NODES + d], 1);
}

__global__ void sumdeg_kernel(const int* __restrict__ cnt8, int* __restrict__ deg) {
    int i = blockIdx.x * blockDim.x + threadIdx.x;
    if (i >= N_NODES) return;
    int s = 0;
#pragma unroll
    for (int s8 = 0; s8 < NSHARD; s8++) s += cnt8[s8 * N_NODES + i];
    deg[i] = s;
}

__global__ __launch_bounds__(1024) void scan1b_kernel(const int* __restrict__ deg,
                                                      int* __restrict__ indptr) {
    const int T = 1024;
    const int C = (N_NODES + T - 1) / T;   // 20 per thread
    __shared__ int sums[T];
    int t = threadIdx.x;
    int base = t * C;
    int local[C];
    int s = 0;
#pragma unroll
    for (int i = 0; i < C; i++) {
        int idx = base + i;
        int v = (idx < N_NODES) ? deg[idx] : 0;
        local[i] = s;
        s += v;
    }
    sums[t] = s;
    __syncthreads();
    for (int off = 1; off < T; off <<= 1) {
        int v = (t >= off) ? sums[t - off] : 0;
        __syncthreads();
        sums[t] += v;
        __syncthreads();
    }
    int prefix = (t == 0) ? 0 : sums[t - 1];
#pragma unroll
    for (int i = 0; i < C; i++) {
        int idx = base + i;
        if (idx < N_NODES) indptr[idx] = prefix + local[i];
    }
    if (t == T - 1) indptr[N_NODES] = prefix + s;   // == E_TOT
}

__global__ void cursor_kernel(const int* __restrict__ indptr, int* __restrict__ cnt8) {
    int i = blockIdx.x * blockDim.x + threadIdx.x;
    if (i >= N_NODES) return;
    int running = indptr[i];
#pragma unroll
    for (int s8 = 0; s8 < NSHARD; s8++) {
        int c = cnt8[s8 * N_NODES + i];
        cnt8[s8 * N_NODES + i] = running;
        running += c;
    }
}

__global__ void scatter_edges_kernel(const int* __restrict__ edge_src,
                                     const int* __restrict__ edge_dst,
                                     int* __restrict__ cnt8,
                                     int* __restrict__ ssrc) {
    int i = blockIdx.x * blockDim.x + threadIdx.x;
    if (i >= E_TOT) return;
    int shard = blockIdx.x & (NSHARD - 1);
    int d, s;
    if (i < N_EDGES) { d = edge_dst[i]; s = edge_src[i]; }
    else             { d = i - N_EDGES; s = d; }
    int pos = atomicAdd(&cnt8[shard * N_NODES + d], 1);   // absolute cursor
    ssrc[pos] = s;
}

// ---------------- GEMM1 fused with row-normalize: x@W1+b1, relu, L2-norm -> bf16 hn + r ----
// Block: 16 rows x 256 cols (grid 1250). Thread t: row = t>>4, colgroup cg = t&15
// (16 cols each). Row's 16 threads are consecutive lanes -> shfl norm reduction.
// Quad reads/writes rotated by cg ((j+cg)&3) to keep LDS conflicts <= 2-way.

__global__ __launch_bounds__(256) void gemm1_norm_kernel(const float* __restrict__ A,
                                                         const float* __restrict__ W,
                                                         const float* __restrict__ bias,
                                                         unsigned short* __restrict__ hnb,
                                                         float* __restrict__ r) {
    __shared__ float As[16][20];
    __shared__ float Bs[16][260];
    int t = threadIdx.x;
    int row = t >> 4;
    int cg  = t & 15;
    int grow = blockIdx.x * 16 + row;
    int c0 = cg * 16;
    float4 acc[4];   // acc[jj] = cols c0+4*jj .. +3
    acc[0] = make_float4(0.f, 0.f, 0.f, 0.f);
    acc[1] = acc[0]; acc[2] = acc[0]; acc[3] = acc[0];

    for (int k0 = 0; k0 < IN_DIM; k0 += 16) {
        {   // stage A 16x16 (1 elem/thread, k-fast for coalescing)
            int r2 = t >> 4, k2 = t & 15;
            As[r2][k2] = A[(long)(blockIdx.x * 16 + r2) * IN_DIM + k0 + k2];
        }
        {   // stage B 16x256 (4 float4/thread, rotated quad order)
            int kr = t >> 4;
            int ccg = t & 15;
            const float4* src = (const float4*)&W[(long)(k0 + kr) * HIDDEN + ccg * 16];
#pragma unroll
            for (int j = 0; j < 4; j++) {
                int jj = (j + ccg) & 3;
                *((float4*)&Bs[kr][ccg * 16 + jj * 4]) = src[jj];
            }
        }
        __syncthreads();
#pragma unroll
        for (int kk = 0; kk < 16; kk++) {
            float a = As[row][kk];
#pragma unroll
            for (int j = 0; j < 4; j++) {
                int jj = (j + cg) & 3;
                float4 q = *((const float4*)&Bs[kk][c0 + jj * 4]);
                acc[jj].x += a * q.x; acc[jj].y += a * q.y;
                acc[jj].z += a * q.z; acc[jj].w += a * q.w;
            }
        }
        __syncthreads();
    }

    float ss = 0.f;
#pragma unroll
    for (int jj = 0; jj < 4; jj++) {
        float4 bv = *((const float4*)&bias[c0 + jj * 4]);
        float4 v = acc[jj];
        v.x = fmaxf(v.x + bv.x, 0.f);
        v.y = fmaxf(v.y + bv.y, 0.f);
        v.z = fmaxf(v.z + bv.z, 0.f);
        v.w = fmaxf(v.w + bv.w, 0.f);
        acc[jj] = v;
        ss += v.x * v.x + v.y * v.y + v.z * v.z + v.w * v.w;
    }
    ss += __shfl_xor(ss, 1);
    ss += __shfl_xor(ss, 2);
    ss += __shfl_xor(ss, 4);
    ss += __shfl_xor(ss, 8);      // full row = 16 consecutive lanes
    float rr = sqrtf(ss + 1e-12f);
    float ir = 1.f / rr;
    uint4 o1, o2;
    o1.x = pk2(acc[0].x * ir, acc[0].y * ir); o1.y = pk2(acc[0].z * ir, acc[0].w * ir);
    o1.z = pk2(acc[1].x * ir, acc[1].y * ir); o1.w = pk2(acc[1].z * ir, acc[1].w * ir);
    o2.x = pk2(acc[2].x * ir, acc[2].y * ir); o2.y = pk2(acc[2].z * ir, acc[2].w * ir);
    o2.z = pk2(acc[3].x * ir, acc[3].y * ir); o2.w = pk2(acc[3].z * ir, acc[3].w * ir);
    uint4* dst = (uint4*)(hnb + (long)grow * HIDDEN + c0);
    dst[0] = o1;
    dst[1] = o2;
    if (cg == 0) r[grow] = rr;
}

// ---------------- fp32 tiled GEMM + bias (GEMM2, R3-proven form) ----------------

__global__ __launch_bounds__(256) void gemm_bias_act(const float* __restrict__ A,
                                                     const float* __restrict__ B,
                                                     const float* __restrict__ bias,
                                                     float* __restrict__ C,
                                                     int M, int Nn, int K, int relu) {
    __shared__ float As[16][65];
    __shared__ float Bs[16][65];
    int tid = threadIdx.x;
    int tx = tid & 15, ty = tid >> 4;
    int row0 = blockIdx.x * 64, col0 = blockIdx.y * 64;
    float acc[4][4] = {};
    for (int k0 = 0; k0 < K; k0 += 16) {
        {
            int r_ = tid >> 2;
            int kq = (tid & 3) * 4;
            int gr = row0 + r_;
            float4 a4 = make_float4(0.f, 0.f, 0.f, 0.f);
            if (gr < M) a4 = *(const float4*)&A[(long)gr * K + k0 + kq];
            As[kq + 0][r_] = a4.x; As[kq + 1][r_] = a4.y;
            As[kq + 2][r_] = a4.z; As[kq + 3][r_] = a4.w;
        }
        {
            int kr = tid >> 4;
            int cq = (tid & 15) * 4;
            float4 b4 = *(const float4*)&B[(long)(k0 + kr) * Nn + col0 + cq];
            Bs[kr][cq + 0] = b4.x; Bs[kr][cq + 1] = b4.y;
            Bs[kr][cq + 2] = b4.z; Bs[kr][cq + 3] = b4.w;
        }
        __syncthreads();
#pragma unroll
        for (int kk = 0; kk < 16; kk++) {
            float a[4], b[4];
#pragma unroll
            for (int i = 0; i < 4; i++) a[i] = As[kk][ty * 4 + i];
#pragma unroll
            for (int j = 0; j < 4; j++) b[j] = Bs[kk][tx * 4 + j];
#pragma unroll
            for (int i = 0; i < 4; i++)
#pragma unroll
                for (int j = 0; j < 4; j++) acc[i][j] += a[i] * b[j];
        }
        __syncthreads();
    }
#pragma unroll
    for (int i = 0; i < 4; i++) {
        int gr = row0 + ty * 4 + i;
        if (gr >= M) continue;
#pragma unroll
        for (int j = 0; j < 4; j++) {
            int gc = col0 + tx * 4 + j;
            float v = acc[i][j] + bias[gc];
            if (relu) v = fmaxf(v, 0.f);
            C[(long)gr * Nn + gc] = v;
        }
    }
}

// ---------------- fused AGNN layer ----------------
// ONE node per wave; edge list split across four 16-lane groups (4 streams).
// Prefetches GUARDED (group-uniform branches) instead of clamped: no redundant
// tail gathers. Stale regs only consumed under w=0 masks; initialized finite.
// No-max softmax (cosine logits bounded): merge = plain sums, 2 shfl rounds.

__global__ __launch_bounds__(256) void agnn_kernel(const unsigned short* __restrict__ hnb,
                                                   const float* __restrict__ rin,
                                                   const int* __restrict__ indptr,
                                                   const int* __restrict__ ssrc,
                                                   unsigned short* __restrict__ hnout,
                                                   float* __restrict__ rout,
                                                   float* __restrict__ hout,
                                                   int write_hn) {
    int lane = threadIdx.x & 63;
    int wid  = threadIdx.x >> 6;
    int sub  = lane >> 4;          // which quarter of the edge list (0..3)
    int gl   = lane & 15;          // lane in 16-group
    int node = blockIdx.x * 4 + wid;   // grid exact: 5000*4 = 20000

    const uint4* tab4 = (const uint4*)hnb;   // one uint4 = 8 bf16; row = 32 uint4
    long nb = (long)node * 32 + gl * 2;
    uint4 ha = tab4[nb], hb = tab4[nb + 1];
    f32x2 hd2[8];
    hd2[0] = up2(ha.x) * LOG2E; hd2[1] = up2(ha.y) * LOG2E;
    hd2[2] = up2(ha.z) * LOG2E; hd2[3] = up2(ha.w) * LOG2E;
    hd2[4] = up2(hb.x) * LOG2E; hd2[5] = up2(hb.y) * LOG2E;
    hd2[6] = up2(hb.z) * LOG2E; hd2[7] = up2(hb.w) * LOG2E;

    int beg = indptr[node], end = indptr[node + 1];
    int deg = end - beg;               // >= 1 (self loop)
    int qb  = deg >> 2, rem = deg & 3;
    int cnt = qb + (sub < rem ? 1 : 0);
    int eb  = beg + sub * qb + min(sub, rem);
    int nmax = qb + (rem ? 1 : 0);     // uniform wave loop bound

    f32x2 acc[8];
#pragma unroll
    for (int p = 0; p < 8; p++) acc[p] = (f32x2)0.f;
    float z = 0.f;

    // guarded 3-deep pipeline prologue
    int s0 = ssrc[(cnt > 0) ? eb : beg];
    long b0 = (long)s0 * 32 + gl * 2;
    uint4 v0a = tab4[b0], v0b = tab4[b0 + 1];
    float r0 = rin[s0];
    uint4 v1a = v0a, v1b = v0b;        // finite defaults for masked tails
    float r1 = 0.f;
    int s2 = s0;
    if (cnt >= 2) {
        int s1 = ssrc[eb + 1];
        long b1 = (long)s1 * 32 + gl * 2;
        v1a = tab4[b1]; v1b = tab4[b1 + 1];
        r1 = rin[s1];
    }
    if (cnt >= 3) s2 = ssrc[eb + 2];

    for (int i = 0; i < nmax; i++) {
        uint4 ca = v0a, cb = v0b;
        float cr = r0;
        v0a = v1a; v0b = v1b; r0 = r1;
        if (i + 2 < cnt) {             // group-uniform guard: no wasted gathers
            long b2 = (long)s2 * 32 + gl * 2;
            v1a = tab4[b2]; v1b = tab4[b2 + 1];
            r1 = rin[s2];
        }
        if (i + 3 < cnt) s2 = ssrc[eb + i + 3];

        f32x2 cf[8];
        cf[0] = up2(ca.x); cf[1] = up2(ca.y); cf[2] = up2(ca.z); cf[3] = up2(ca.w);
        cf[4] = up2(cb.x); cf[5] = up2(cb.y); cf[6] = up2(cb.z); cf[7] = up2(cb.w);
        f32x2 da = cf[0] * hd2[0];
        f32x2 db = cf[1] * hd2[1];
        da += cf[2] * hd2[2];  db += cf[3] * hd2[3];
        da += cf[4] * hd2[4];  db += cf[5] * hd2[5];
        da += cf[6] * hd2[6];  db += cf[7] * hd2[7];
        f32x2 d2 = da + db;
        float d = d2.x + d2.y;
        d += __shfl_xor(d, 1);
        d += __shfl_xor(d, 2);
        d += __shfl_xor(d, 4);
        d += __shfl_xor(d, 8);
        float w = (i < cnt) ? exp2f(d) : 0.f;   // mask tail of shorter streams
        z += w;
        float wr = w * cr;
#pragma unroll
        for (int p = 0; p < 8; p++) acc[p] += cf[p] * wr;
    }

    // merge the 4 partial streams (plain sums -- no max state)
    z += __shfl_xor(z, 16);
    z += __shfl_xor(z, 32);
#pragma unroll
    for (int p = 0; p < 8; p++) {
        acc[p].x += __shfl_xor(acc[p].x, 16);
        acc[p].y += __shfl_xor(acc[p].y, 16);
        acc[p].x += __shfl_xor(acc[p].x, 32);
        acc[p].y += __shfl_xor(acc[p].y, 32);
    }

    float inv = 1.f / z;
    f32x2 o[8];
#pragma unroll
    for (int p = 0; p < 8; p++) {
        f32x2 t = acc[p] * inv;
        t.x = fmaxf(t.x, 0.f);
        t.y = fmaxf(t.y, 0.f);
        o[p] = t;
    }

    if (write_hn) {
        float ss = 0.f;
#pragma unroll
        for (int p = 0; p < 8; p++) ss += o[p].x * o[p].x + o[p].y * o[p].y;
        ss += __shfl_xor(ss, 1);
        ss += __shfl_xor(ss, 2);
        ss += __shfl_xor(ss, 4);
        ss += __shfl_xor(ss, 8);     // full row lives in each 16-lane group
        float rr = sqrtf(ss + 1e-12f);
        float ir = 1.f / rr;
        if (sub == 0) {
            uint4 oa, ob;
            oa.x = pk2(o[0].x * ir, o[0].y * ir);
            oa.y = pk2(o[1].x * ir, o[1].y * ir);
            oa.z = pk2(o[2].x * ir, o[2].y * ir);
            oa.w = pk2(o[3].x * ir, o[3].y * ir);
            ob.x = pk2(o[4].x * ir, o[4].y * ir);
            ob.y = pk2(o[5].x * ir, o[5].y * ir);
            ob.z = pk2(o[6].x * ir, o[6].y * ir);
            ob.w = pk2(o[7].x * ir, o[7].y * ir);
            uint4* outt = (uint4*)hnout;
            outt[nb] = oa;
            outt[nb + 1] = ob;
            if (gl == 0) rout[node] = rr;
        }
    } else {
        if (sub == 0) {
            float4* ho = (float4*)(hout + (long)node * HIDDEN + gl * 16);
            ho[0] = make_float4(o[0].x, o[0].y, o[1].x, o[1].y);
            ho[1] = make_float4(o[2].x, o[2].y, o[3].x, o[3].y);
            ho[2] = make_float4(o[4].x, o[4].y, o[5].x, o[5].y);
            ho[3] = make_float4(o[6].x, o[6].y, o[7].x, o[7].y);
        }
    }
}

// ---------------- launch (12 kernels) ----------------

extern "C" void kernel_launch(void* const* d_in, const int* in_sizes, int n_in,
                              void* d_out, int out_size, void* d_ws, size_t ws_size,
                              hipStream_t stream) {
    const float* x  = (const float*)d_in[0];
    const int* esrc = (const int*)d_in[1];
    const int* edst = (const int*)d_in[2];
    const float* W1 = (const float*)d_in[3];
    const float* b1 = (const float*)d_in[4];
    const float* W2 = (const float*)d_in[5];
    const float* b2 = (const float*)d_in[6];
    float* out = (float*)d_out;

    char* ws = (char*)d_ws;
    float*          h0     = (float*)(ws);                          // 20,480,000 B
    unsigned short* hnA    = (unsigned short*)(ws + 20480000);      // 10,240,000 B
    unsigned short* hnB    = (unsigned short*)(ws + 30720000);      // 10,240,000 B
    float*          rA     = (float*)(ws + 40960000);               // 80,000 B
    float*          rB     = (float*)(ws + 41040000);               // 80,000 B
    int*            indptr = (int*)  (ws + 41120000);               // 80,004 B (pad)
    int*            cnt8   = (int*)  (ws + 41200256);               // 640,000 B
    int*            ssrc   = (int*)  (ws + 41840256);               // 2,640,000 B
    int*            deg    = (int*)  (ws + 44480256);               // 80,000 B

    zero_cnt8_kernel<<<(NSHARD * N_NODES + 255) / 256, 256, 0, stream>>>(cnt8);
    count_kernel<<<(E_TOT + 255) / 256, 256, 0, stream>>>(edst, cnt8);
    sumdeg_kernel<<<(N_NODES + 255) / 256, 256, 0, stream>>>(cnt8, deg);
    scan1b_kernel<<<1, 1024, 0, stream>>>(deg, indptr);
    cursor_kernel<<<(N_NODES + 255) / 256, 256, 0, stream>>>(indptr, cnt8);
    scatter_edges_kernel<<<(E_TOT + 255) / 256, 256, 0, stream>>>(esrc, edst, cnt8, ssrc);

    gemm1_norm_kernel<<<N_NODES / 16, 256, 0, stream>>>(x, W1, b1, hnA, rA);

    int nblk = N_NODES / 4;   // 5000, exact
    // L0: A -> B, L1: B -> A, L2: A -> B, L3: B -> h0 (fp32)
    agnn_kernel<<<nblk, 256, 0, stream>>>(hnA, rA, indptr, ssrc, hnB, rB, h0, 1);
    agnn_kernel<<<nblk, 256, 0, stream>>>(hnB, rB, indptr, ssrc, hnA, rA, h0, 1);
    agnn_kernel<<<nblk, 256, 0, stream>>>(hnA, rA, indptr, ssrc, hnB, rB, h0, 1);
    agnn_kernel<<<nblk, 256, 0, stream>>>(hnB, rB, indptr, ssrc, hnA, rA, h0, 0);

    dim3 g2((N_NODES + 63) / 64, OUT_DIM / 64);
    gemm_bias_act<<<g2, 256, 0, stream>>>(h0, W2, b2, out, N_NODES, OUT_DIM, HIDDEN, 0);
}

// Round 10
// 309.909 us; speedup vs baseline: 5.7354x; 5.7354x over previous
//
#include <hip/hip_runtime.h>

#define N_NODES 20000
#define N_EDGES 640000
#define E_TOT   (N_EDGES + N_NODES)   /* 660000: edges + self loops */
#define IN_DIM  128
#define HIDDEN  256
#define OUT_DIM 64
#define LOG2E 1.4426950408889634f
#define NSHARD 8

typedef __attribute__((ext_vector_type(2))) float f32x2;

__device__ __forceinline__ unsigned short f2bf(float f) {
    union { float f; unsigned int i; } x; x.f = f;
    unsigned int u = x.i;
    return (unsigned short)((u + 0x7fffu + ((u >> 16) & 1u)) >> 16);  // RTNE
}
__device__ __forceinline__ f32x2 up2(unsigned int p) {   // 2 packed bf16 -> 2 fp32
    f32x2 r;
    r.x = __uint_as_float(p << 16);
    r.y = __uint_as_float(p & 0xffff0000u);
    return r;
}
__device__ __forceinline__ unsigned int pk2(float a, float b) {
    return (unsigned int)f2bf(a) | ((unsigned int)f2bf(b) << 16);
}

// ---------------- CSR build (6 kernels, all O(N*8) phases grid-parallel) ----------------

__global__ void zero_cnt8_kernel(int* __restrict__ cnt8) {
    int i = blockIdx.x * blockDim.x + threadIdx.x;
    if (i < NSHARD * N_NODES) cnt8[i] = 0;
}

__global__ void count_kernel(const int* __restrict__ edge_dst, int* __restrict__ cnt8) {
    int i = blockIdx.x * blockDim.x + threadIdx.x;
    if (i >= E_TOT) return;
    int shard = blockIdx.x & (NSHARD - 1);
    int d = (i < N_EDGES) ? edge_dst[i] : (i - N_EDGES);   // implicit self-loop tail
    atomicAdd(&cnt8[shard * N_NODES + d], 1);
}

__global__ void sumdeg_kernel(const int* __restrict__ cnt8, int* __restrict__ deg) {
    int i = blockIdx.x * blockDim.x + threadIdx.x;
    if (i >= N_NODES) return;
    int s = 0;
#pragma unroll
    for (int s8 = 0; s8 < NSHARD; s8++) s += cnt8[s8 * N_NODES + i];
    deg[i] = s;
}

__global__ __launch_bounds__(1024) void scan1b_kernel(const int* __restrict__ deg,
                                                      int* __restrict__ indptr) {
    const int T = 1024;
    const int C = (N_NODES + T - 1) / T;   // 20 per thread
    __shared__ int sums[T];
    int t = threadIdx.x;
    int base = t * C;
    int local[C];
    int s = 0;
#pragma unroll
    for (int i = 0; i < C; i++) {
        int idx = base + i;
        int v = (idx < N_NODES) ? deg[idx] : 0;
        local[i] = s;
        s += v;
    }
    sums[t] = s;
    __syncthreads();
    for (int off = 1; off < T; off <<= 1) {
        int v = (t >= off) ? sums[t - off] : 0;
        __syncthreads();
        sums[t] += v;
        __syncthreads();
    }
    int prefix = (t == 0) ? 0 : sums[t - 1];
#pragma unroll
    for (int i = 0; i < C; i++) {
        int idx = base + i;
        if (idx < N_NODES) indptr[idx] = prefix + local[i];
    }
    if (t == T - 1) indptr[N_NODES] = prefix + s;   // == E_TOT
}

__global__ void cursor_kernel(const int* __restrict__ indptr, int* __restrict__ cnt8) {
    int i = blockIdx.x * blockDim.x + threadIdx.x;
    if (i >= N_NODES) return;
    int running = indptr[i];
#pragma unroll
    for (int s8 = 0; s8 < NSHARD; s8++) {
        int c = cnt8[s8 * N_NODES + i];
        cnt8[s8 * N_NODES + i] = running;
        running += c;
    }
}

__global__ void scatter_edges_kernel(const int* __restrict__ edge_src,
                                     const int* __restrict__ edge_dst,
                                     int* __restrict__ cnt8,
                                     int* __restrict__ ssrc) {
    int i = blockIdx.x * blockDim.x + threadIdx.x;
    if (i >= E_TOT) return;
    int shard = blockIdx.x & (NSHARD - 1);
    int d, s;
    if (i < N_EDGES) { d = edge_dst[i]; s = edge_src[i]; }
    else             { d = i - N_EDGES; s = d; }
    int pos = atomicAdd(&cnt8[shard * N_NODES + d], 1);   // absolute cursor
    ssrc[pos] = s;
}

// ---------------- GEMM1 fused with row-normalize: x@W1+b1, relu, L2-norm -> bf16 hn + r ----
// Block: 16 rows x 256 cols (grid 1250). Thread t: row = t>>4, cg = t&15.
// Thread cg owns SCATTERED column quads {4*cg + 64*j, j=0..3}:
//  - acc[] indexed ONLY by unrolled literal j (no runtime index -> stays in VGPRs;
//    R8's rotated acc[(j+cg)&3] was demoted to scratch: 177 MB writes, 1555 us)
//  - LDS read banks = 4*cg mod 32 -> 2-way conflict (free); row-groups broadcast
//  - global loads/stores per j are 16 consecutive float4/uint2 -> coalesced

__global__ __launch_bounds__(256) void gemm1_norm_kernel(const float* __restrict__ A,
                                                         const float* __restrict__ W,
                                                         const float* __restrict__ bias,
                                                         unsigned short* __restrict__ hnb,
                                                         float* __restrict__ r) {
    __shared__ float As[16][20];
    __shared__ float Bs[16][260];
    int t = threadIdx.x;
    int row = t >> 4;
    int cg  = t & 15;
    int grow = blockIdx.x * 16 + row;
    float4 acc0 = make_float4(0.f, 0.f, 0.f, 0.f);
    float4 acc1 = acc0, acc2 = acc0, acc3 = acc0;

    for (int k0 = 0; k0 < IN_DIM; k0 += 16) {
        {   // stage A 16x16 (1 elem/thread, k-fast)
            As[row][cg] = A[(long)grow * IN_DIM + k0 + cg];
        }
        {   // stage B 16x256: thread (kr,ccg) writes quads 4*ccg+64*j
            const float4* src = (const float4*)&W[(long)(k0 + row) * HIDDEN];
#pragma unroll
            for (int j = 0; j < 4; j++)
                *((float4*)&Bs[row][4 * cg + 64 * j]) = src[cg + 16 * j];
        }
        __syncthreads();
#pragma unroll
        for (int kk = 0; kk < 16; kk++) {
            float a = As[row][kk];
            float4 q0 = *((const float4*)&Bs[kk][4 * cg]);
            float4 q1 = *((const float4*)&Bs[kk][4 * cg + 64]);
            float4 q2 = *((const float4*)&Bs[kk][4 * cg + 128]);
            float4 q3 = *((const float4*)&Bs[kk][4 * cg + 192]);
            acc0.x += a * q0.x; acc0.y += a * q0.y; acc0.z += a * q0.z; acc0.w += a * q0.w;
            acc1.x += a * q1.x; acc1.y += a * q1.y; acc1.z += a * q1.z; acc1.w += a * q1.w;
            acc2.x += a * q2.x; acc2.y += a * q2.y; acc2.z += a * q2.z; acc2.w += a * q2.w;
            acc3.x += a * q3.x; acc3.y += a * q3.y; acc3.z += a * q3.z; acc3.w += a * q3.w;
        }
        __syncthreads();
    }

    // bias + relu + squared-sum (static names throughout)
    float ss = 0.f;
    {
        float4 bv = *((const float4*)&bias[4 * cg]);
        acc0.x = fmaxf(acc0.x + bv.x, 0.f); acc0.y = fmaxf(acc0.y + bv.y, 0.f);
        acc0.z = fmaxf(acc0.z + bv.z, 0.f); acc0.w = fmaxf(acc0.w + bv.w, 0.f);
        ss += acc0.x * acc0.x + acc0.y * acc0.y + acc0.z * acc0.z + acc0.w * acc0.w;
    }
    {
        float4 bv = *((const float4*)&bias[4 * cg + 64]);
        acc1.x = fmaxf(acc1.x + bv.x, 0.f); acc1.y = fmaxf(acc1.y + bv.y, 0.f);
        acc1.z = fmaxf(acc1.z + bv.z, 0.f); acc1.w = fmaxf(acc1.w + bv.w, 0.f);
        ss += acc1.x * acc1.x + acc1.y * acc1.y + acc1.z * acc1.z + acc1.w * acc1.w;
    }
    {
        float4 bv = *((const float4*)&bias[4 * cg + 128]);
        acc2.x = fmaxf(acc2.x + bv.x, 0.f); acc2.y = fmaxf(acc2.y + bv.y, 0.f);
        acc2.z = fmaxf(acc2.z + bv.z, 0.f); acc2.w = fmaxf(acc2.w + bv.w, 0.f);
        ss += acc2.x * acc2.x + acc2.y * acc2.y + acc2.z * acc2.z + acc2.w * acc2.w;
    }
    {
        float4 bv = *((const float4*)&bias[4 * cg + 192]);
        acc3.x = fmaxf(acc3.x + bv.x, 0.f); acc3.y = fmaxf(acc3.y + bv.y, 0.f);
        acc3.z = fmaxf(acc3.z + bv.z, 0.f); acc3.w = fmaxf(acc3.w + bv.w, 0.f);
        ss += acc3.x * acc3.x + acc3.y * acc3.y + acc3.z * acc3.z + acc3.w * acc3.w;
    }
    ss += __shfl_xor(ss, 1);
    ss += __shfl_xor(ss, 2);
    ss += __shfl_xor(ss, 4);
    ss += __shfl_xor(ss, 8);      // full row = 16 consecutive lanes
    float rr = sqrtf(ss + 1e-12f);
    float ir = 1.f / rr;
    uint2* dst = (uint2*)(hnb + (long)grow * HIDDEN);
    uint2 o;
    o.x = pk2(acc0.x * ir, acc0.y * ir); o.y = pk2(acc0.z * ir, acc0.w * ir);
    dst[cg]      = o;
    o.x = pk2(acc1.x * ir, acc1.y * ir); o.y = pk2(acc1.z * ir, acc1.w * ir);
    dst[cg + 16] = o;
    o.x = pk2(acc2.x * ir, acc2.y * ir); o.y = pk2(acc2.z * ir, acc2.w * ir);
    dst[cg + 32] = o;
    o.x = pk2(acc3.x * ir, acc3.y * ir); o.y = pk2(acc3.z * ir, acc3.w * ir);
    dst[cg + 48] = o;
    if (cg == 0) r[grow] = rr;
}

// ---------------- fp32 tiled GEMM + bias (GEMM2, R3-proven form) ----------------

__global__ __launch_bounds__(256) void gemm_bias_act(const float* __restrict__ A,
                                                     const float* __restrict__ B,
                                                     const float* __restrict__ bias,
                                                     float* __restrict__ C,
                                                     int M, int Nn, int K, int relu) {
    __shared__ float As[16][65];
    __shared__ float Bs[16][65];
    int tid = threadIdx.x;
    int tx = tid & 15, ty = tid >> 4;
    int row0 = blockIdx.x * 64, col0 = blockIdx.y * 64;
    float acc[4][4] = {};
    for (int k0 = 0; k0 < K; k0 += 16) {
        {
            int r_ = tid >> 2;
            int kq = (tid & 3) * 4;
            int gr = row0 + r_;
            float4 a4 = make_float4(0.f, 0.f, 0.f, 0.f);
            if (gr < M) a4 = *(const float4*)&A[(long)gr * K + k0 + kq];
            As[kq + 0][r_] = a4.x; As[kq + 1][r_] = a4.y;
            As[kq + 2][r_] = a4.z; As[kq + 3][r_] = a4.w;
        }
        {
            int kr = tid >> 4;
            int cq = (tid & 15) * 4;
            float4 b4 = *(const float4*)&B[(long)(k0 + kr) * Nn + col0 + cq];
            Bs[kr][cq + 0] = b4.x; Bs[kr][cq + 1] = b4.y;
            Bs[kr][cq + 2] = b4.z; Bs[kr][cq + 3] = b4.w;
        }
        __syncthreads();
#pragma unroll
        for (int kk = 0; kk < 16; kk++) {
            float a[4], b[4];
#pragma unroll
            for (int i = 0; i < 4; i++) a[i] = As[kk][ty * 4 + i];
#pragma unroll
            for (int j = 0; j < 4; j++) b[j] = Bs[kk][tx * 4 + j];
#pragma unroll
            for (int i = 0; i < 4; i++)
#pragma unroll
                for (int j = 0; j < 4; j++) acc[i][j] += a[i] * b[j];
        }
        __syncthreads();
    }
#pragma unroll
    for (int i = 0; i < 4; i++) {
        int gr = row0 + ty * 4 + i;
        if (gr >= M) continue;
#pragma unroll
        for (int j = 0; j < 4; j++) {
            int gc = col0 + tx * 4 + j;
            float v = acc[i][j] + bias[gc];
            if (relu) v = fmaxf(v, 0.f);
            C[(long)gr * Nn + gc] = v;
        }
    }
}

// ---------------- fused AGNN layer (R8 form: guarded prefetch) ----------------

__global__ __launch_bounds__(256) void agnn_kernel(const unsigned short* __restrict__ hnb,
                                                   const float* __restrict__ rin,
                                                   const int* __restrict__ indptr,
                                                   const int* __restrict__ ssrc,
                                                   unsigned short* __restrict__ hnout,
                                                   float* __restrict__ rout,
                                                   float* __restrict__ hout,
                                                   int write_hn) {
    int lane = threadIdx.x & 63;
    int wid  = threadIdx.x >> 6;
    int sub  = lane >> 4;          // which quarter of the edge list (0..3)
    int gl   = lane & 15;          // lane in 16-group
    int node = blockIdx.x * 4 + wid;   // grid exact: 5000*4 = 20000

    const uint4* tab4 = (const uint4*)hnb;   // one uint4 = 8 bf16; row = 32 uint4
    long nb = (long)node * 32 + gl * 2;
    uint4 ha = tab4[nb], hb = tab4[nb + 1];
    f32x2 hd2[8];
    hd2[0] = up2(ha.x) * LOG2E; hd2[1] = up2(ha.y) * LOG2E;
    hd2[2] = up2(ha.z) * LOG2E; hd2[3] = up2(ha.w) * LOG2E;
    hd2[4] = up2(hb.x) * LOG2E; hd2[5] = up2(hb.y) * LOG2E;
    hd2[6] = up2(hb.z) * LOG2E; hd2[7] = up2(hb.w) * LOG2E;

    int beg = indptr[node], end = indptr[node + 1];
    int deg = end - beg;               // >= 1 (self loop)
    int qb  = deg >> 2, rem = deg & 3;
    int cnt = qb + (sub < rem ? 1 : 0);
    int eb  = beg + sub * qb + min(sub, rem);
    int nmax = qb + (rem ? 1 : 0);     // uniform wave loop bound

    f32x2 acc[8];
#pragma unroll
    for (int p = 0; p < 8; p++) acc[p] = (f32x2)0.f;
    float z = 0.f;

    // guarded 3-deep pipeline prologue
    int s0 = ssrc[(cnt > 0) ? eb : beg];
    long b0 = (long)s0 * 32 + gl * 2;
    uint4 v0a = tab4[b0], v0b = tab4[b0 + 1];
    float r0 = rin[s0];
    uint4 v1a = v0a, v1b = v0b;        // finite defaults for masked tails
    float r1 = 0.f;
    int s2 = s0;
    if (cnt >= 2) {
        int s1 = ssrc[eb + 1];
        long b1 = (long)s1 * 32 + gl * 2;
        v1a = tab4[b1]; v1b = tab4[b1 + 1];
        r1 = rin[s1];
    }
    if (cnt >= 3) s2 = ssrc[eb + 2];

    for (int i = 0; i < nmax; i++) {
        uint4 ca = v0a, cb = v0b;
        float cr = r0;
        v0a = v1a; v0b = v1b; r0 = r1;
        if (i + 2 < cnt) {             // group-uniform guard: no wasted gathers
            long b2 = (long)s2 * 32 + gl * 2;
            v1a = tab4[b2]; v1b = tab4[b2 + 1];
            r1 = rin[s2];
        }
        if (i + 3 < cnt) s2 = ssrc[eb + i + 3];

        f32x2 cf[8];
        cf[0] = up2(ca.x); cf[1] = up2(ca.y); cf[2] = up2(ca.z); cf[3] = up2(ca.w);
        cf[4] = up2(cb.x); cf[5] = up2(cb.y); cf[6] = up2(cb.z); cf[7] = up2(cb.w);
        f32x2 da = cf[0] * hd2[0];
        f32x2 db = cf[1] * hd2[1];
        da += cf[2] * hd2[2];  db += cf[3] * hd2[3];
        da += cf[4] * hd2[4];  db += cf[5] * hd2[5];
        da += cf[6] * hd2[6];  db += cf[7] * hd2[7];
        f32x2 d2 = da + db;
        float d = d2.x + d2.y;
        d += __shfl_xor(d, 1);
        d += __shfl_xor(d, 2);
        d += __shfl_xor(d, 4);
        d += __shfl_xor(d, 8);
        float w = (i < cnt) ? exp2f(d) : 0.f;   // mask tail of shorter streams
        z += w;
        float wr = w * cr;
#pragma unroll
        for (int p = 0; p < 8; p++) acc[p] += cf[p] * wr;
    }

    // merge the 4 partial streams (plain sums -- no max state)
    z += __shfl_xor(z, 16);
    z += __shfl_xor(z, 32);
#pragma unroll
    for (int p = 0; p < 8; p++) {
        acc[p].x += __shfl_xor(acc[p].x, 16);
        acc[p].y += __shfl_xor(acc[p].y, 16);
        acc[p].x += __shfl_xor(acc[p].x, 32);
        acc[p].y += __shfl_xor(acc[p].y, 32);
    }

    float inv = 1.f / z;
    f32x2 o[8];
#pragma unroll
    for (int p = 0; p < 8; p++) {
        f32x2 t = acc[p] * inv;
        t.x = fmaxf(t.x, 0.f);
        t.y = fmaxf(t.y, 0.f);
        o[p] = t;
    }

    if (write_hn) {
        float ss = 0.f;
#pragma unroll
        for (int p = 0; p < 8; p++) ss += o[p].x * o[p].x + o[p].y * o[p].y;
        ss += __shfl_xor(ss, 1);
        ss += __shfl_xor(ss, 2);
        ss += __shfl_xor(ss, 4);
        ss += __shfl_xor(ss, 8);     // full row lives in each 16-lane group
        float rr = sqrtf(ss + 1e-12f);
        float ir = 1.f / rr;
        if (sub == 0) {
            uint4 oa, ob;
            oa.x = pk2(o[0].x * ir, o[0].y * ir);
            oa.y = pk2(o[1].x * ir, o[1].y * ir);
            oa.z = pk2(o[2].x * ir, o[2].y * ir);
            oa.w = pk2(o[3].x * ir, o[3].y * ir);
            ob.x = pk2(o[4].x * ir, o[4].y * ir);
            ob.y = pk2(o[5].x * ir, o[5].y * ir);
            ob.z = pk2(o[6].x * ir, o[6].y * ir);
            ob.w = pk2(o[7].x * ir, o[7].y * ir);
            uint4* outt = (uint4*)hnout;
            outt[nb] = oa;
            outt[nb + 1] = ob;
            if (gl == 0) rout[node] = rr;
        }
    } else {
        if (sub == 0) {
            float4* ho = (float4*)(hout + (long)node * HIDDEN + gl * 16);
            ho[0] = make_float4(o[0].x, o[0].y, o[1].x, o[1].y);
            ho[1] = make_float4(o[2].x, o[2].y, o[3].x, o[3].y);
            ho[2] = make_float4(o[4].x, o[4].y, o[5].x, o[5].y);
            ho[3] = make_float4(o[6].x, o[6].y, o[7].x, o[7].y);
        }
    }
}

// ---------------- launch (12 kernels) ----------------

extern "C" void kernel_launch(void* const* d_in, const int* in_sizes, int n_in,
                              void* d_out, int out_size, void* d_ws, size_t ws_size,
                              hipStream_t stream) {
    const float* x  = (const float*)d_in[0];
    const int* esrc = (const int*)d_in[1];
    const int* edst = (const int*)d_in[2];
    const float* W1 = (const float*)d_in[3];
    const float* b1 = (const float*)d_in[4];
    const float* W2 = (const float*)d_in[5];
    const float* b2 = (const float*)d_in[6];
    float* out = (float*)d_out;

    char* ws = (char*)d_ws;
    float*          h0     = (float*)(ws);                          // 20,480,000 B
    unsigned short* hnA    = (unsigned short*)(ws + 20480000);      // 10,240,000 B
    unsigned short* hnB    = (unsigned short*)(ws + 30720000);      // 10,240,000 B
    float*          rA     = (float*)(ws + 40960000);               // 80,000 B
    float*          rB     = (float*)(ws + 41040000);               // 80,000 B
    int*            indptr = (int*)  (ws + 41120000);               // 80,004 B (pad)
    int*            cnt8   = (int*)  (ws + 41200256);               // 640,000 B
    int*            ssrc   = (int*)  (ws + 41840256);               // 2,640,000 B
    int*            deg    = (int*)  (ws + 44480256);               // 80,000 B

    zero_cnt8_kernel<<<(NSHARD * N_NODES + 255) / 256, 256, 0, stream>>>(cnt8);
    count_kernel<<<(E_TOT + 255) / 256, 256, 0, stream>>>(edst, cnt8);
    sumdeg_kernel<<<(N_NODES + 255) / 256, 256, 0, stream>>>(cnt8, deg);
    scan1b_kernel<<<1, 1024, 0, stream>>>(deg, indptr);
    cursor_kernel<<<(N_NODES + 255) / 256, 256, 0, stream>>>(indptr, cnt8);
    scatter_edges_kernel<<<(E_TOT + 255) / 256, 256, 0, stream>>>(esrc, edst, cnt8, ssrc);

    gemm1_norm_kernel<<<N_NODES / 16, 256, 0, stream>>>(x, W1, b1, hnA, rA);

    int nblk = N_NODES / 4;   // 5000, exact
    // L0: A -> B, L1: B -> A, L2: A -> B, L3: B -> h0 (fp32)
    agnn_kernel<<<nblk, 256, 0, stream>>>(hnA, rA, indptr, ssrc, hnB, rB, h0, 1);
    agnn_kernel<<<nblk, 256, 0, stream>>>(hnB, rB, indptr, ssrc, hnA, rA, h0, 1);
    agnn_kernel<<<nblk, 256, 0, stream>>>(hnA, rA, indptr, ssrc, hnB, rB, h0, 1);
    agnn_kernel<<<nblk, 256, 0, stream>>>(hnB, rB, indptr, ssrc, hnA, rA, h0, 0);

    dim3 g2((N_NODES + 63) / 64, OUT_DIM / 64);
    gemm_bias_act<<<g2, 256, 0, stream>>>(h0, W2, b2, out, N_NODES, OUT_DIM, HIDDEN, 0);
}